// Round 10
// baseline (2085.081 us; speedup 1.0000x reference)
//
#include <hip/hip_runtime.h>
#include <hip/hip_cooperative_groups.h>

namespace cg = cooperative_groups;

#define NB 64      // batch
#define NC 32      // channels
#define PLANE 256  // 16*16
#define NK 4096    // codebook size
#define NWAVES 4096  // fused grid: 1024 blocks x 4 waves

// ---------------- cubic (Keys a=-0.5), matches jax.image.resize 'cubic' ----
__device__ __forceinline__ float cubic_w(float x) {
    x = fabsf(x);
    if (x >= 2.f) return 0.f;
    if (x >= 1.f) return ((-0.5f * x + 2.5f) * x - 4.f) * x + 2.f;
    return ((1.5f * x - 2.5f) * x) * x + 1.f;
}

template <int PN>
__device__ __forceinline__ void taps(int o, float* w, int& i0, int& n) {
    float sf = (o + 0.5f) * ((float)PN / 16.f) - 0.5f;
    int lo = (int)floorf(sf) - 1;
    int hi = lo + 3;
    if (lo < 0) lo = 0;
    if (hi > PN - 1) hi = PN - 1;
    n = hi - lo + 1;
    i0 = lo;
    float tot = 0.f;
    for (int i = 0; i < n; i++) {
        float ww = cubic_w(sf - (float)(lo + i));
        w[i] = ww;
        tot += ww;
    }
    float inv = 1.f / tot;
    for (int i = 0; i < n; i++) w[i] *= inv;
}

// ---- exact-order helpers (match numpy reference rounding; do not touch) ----
#define FMA4(D, A, B)                                                          \
    D = __builtin_fmaf((A).x, (B).x, D); D = __builtin_fmaf((A).y, (B).y, D);  \
    D = __builtin_fmaf((A).z, (B).z, D); D = __builtin_fmaf((A).w, (B).w, D)
#define DOT32(D)                                                               \
    FMA4(D, z0, w0); FMA4(D, z1, w1); FMA4(D, z2, w2); FMA4(D, z3, w3);        \
    FMA4(D, z4, w4); FMA4(D, z5, w5); FMA4(D, z6, w6); FMA4(D, z7, w7)
#define DOT32_2(DA, DB)                                                        \
    FMA4(DA, a0, w0); FMA4(DB, b0, w0); FMA4(DA, a1, w1); FMA4(DB, b1, w1);    \
    FMA4(DA, a2, w2); FMA4(DB, b2, w2); FMA4(DA, a3, w3); FMA4(DB, b3, w3);    \
    FMA4(DA, a4, w4); FMA4(DB, b4, w4); FMA4(DA, a5, w5); FMA4(DB, b5, w5);    \
    FMA4(DA, a6, w6); FMA4(DB, b6, w6); FMA4(DA, a7, w7); FMA4(DB, b7, w7)

__device__ __forceinline__ float pairwise_zsq(float4 z0, float4 z1, float4 z2,
                                              float4 z3, float4 z4, float4 z5,
                                              float4 z6, float4 z7) {
#define SQ_(a) __fmul_rn((a), (a))
#define R4_(a, b, c, d) \
    __fadd_rn(__fadd_rn(__fadd_rn(SQ_(a), SQ_(b)), SQ_(c)), SQ_(d))
    float r0 = R4_(z0.x, z2.x, z4.x, z6.x);
    float r1 = R4_(z0.y, z2.y, z4.y, z6.y);
    float r2 = R4_(z0.z, z2.z, z4.z, z6.z);
    float r3 = R4_(z0.w, z2.w, z4.w, z6.w);
    float r4 = R4_(z1.x, z3.x, z5.x, z7.x);
    float r5 = R4_(z1.y, z3.y, z5.y, z7.y);
    float r6 = R4_(z1.z, z3.z, z5.z, z7.z);
    float r7 = R4_(z1.w, z3.w, z5.w, z7.w);
    return __fadd_rn(__fadd_rn(__fadd_rn(r0, r1), __fadd_rn(r2, r3)),
                     __fadd_rn(__fadd_rn(r4, r5), __fadd_rn(r6, r7)));
#undef R4_
#undef SQ_
}

// ============ device phase bodies (shared by fused + fallback paths) ========

// init: block blk does planes 2blk,2blk+1 (exact original per-plane reduction
// order) and wsq rows 4blk..4blk+3 (exact original 32-lane shfl tree).
__device__ __forceinline__ void dev_init(int blk, int t,
    const float* __restrict__ z_enc, const float* __restrict__ emb,
    float* __restrict__ zflat0, float* __restrict__ wsq, float* p) {
    for (int i = 0; i < 2; i++) {
        int bc = blk * 2 + i;
        float v = z_enc[bc * PLANE + t];
        for (int o = 32; o > 0; o >>= 1) v += __shfl_down(v, o, 64);
        if ((t & 63) == 0) p[t >> 6] = v;
        __syncthreads();
        if (t == 0) zflat0[bc] = (p[0] + p[1] + p[2] + p[3]) * (1.f / 256.f);
        __syncthreads();
    }
    if (t < 128) {
        int k = blk * 4 + (t >> 5);
        int c = t & 31;
        float e = emb[k * 32 + c];
        float s = __fmul_rn(e, e);
        for (int o = 16; o > 0; o >>= 1) s += __shfl_down(s, o, 32);
        if (c == 0) wsq[k] = s;
    }
}

// k-parallel partial (levels 0,1): wave-task gw -> (tok = gw>>4, chunk = gw&15),
// KPL=4, kbase = chunk*256. Exact per-k dist + wave lex (d,k) reduce.
template <int T>
__device__ __forceinline__ void dev_partk(int gw, int lane,
    const float* __restrict__ zflat, const float* __restrict__ emb,
    const float* __restrict__ wsq, float* __restrict__ cand_d,
    int* __restrict__ cand_i) {
    if (gw < T * 16) {
        int tok = gw >> 4;
        int chunk = gw & 15;
        int kbase = chunk * 256;
        const float4* zr = (const float4*)(zflat + (size_t)tok * 32);
        float4 z0 = zr[0], z1 = zr[1], z2 = zr[2], z3 = zr[3];
        float4 z4 = zr[4], z5 = zr[5], z6 = zr[6], z7 = zr[7];
        float zsq = pairwise_zsq(z0, z1, z2, z3, z4, z5, z6, z7);
        float best = 1e30f;
        int bi = 0;
#pragma unroll
        for (int j = 0; j < 4; j++) {
            int k = kbase + j * 64 + lane;   // ascending per lane
            const float4* wr = (const float4*)emb + (size_t)k * 8;  // per-lane
            float4 w0 = wr[0], w1 = wr[1], w2 = wr[2], w3 = wr[3];
            float4 w4 = wr[4], w5 = wr[5], w6 = wr[6], w7 = wr[7];
            float dot = 0.f;
            DOT32(dot);
            float d = __fsub_rn(__fadd_rn(zsq, wsq[k]), __fmul_rn(2.f, dot));
            if (d < best) { best = d; bi = k; }
        }
        for (int off = 32; off > 0; off >>= 1) {
            float od = __shfl_down(best, off, 64);
            int oi = __shfl_down(bi, off, 64);
            if (od < best || (od == best && oi < bi)) { best = od; bi = oi; }
        }
        if (lane == 0) {
            cand_d[(size_t)tok * 16 + chunk] = best;
            cand_i[(size_t)tok * 16 + chunk] = bi;
        }
    }
}

// token-parallel partial, 2 tok/lane (levels 2-4): wave-task gw ->
// (tg = gw/KS, chunk = gw%KS); exactly NWAVES tasks per level. Exact
// sequential fp32 fma chain per token; strict < over ascending k.
template <int CPK, int KS>
__device__ __forceinline__ void dev_part2(int gw, int lane,
    const float* __restrict__ zflat, const float* __restrict__ emb,
    const float* __restrict__ wsq, float* __restrict__ cand_d,
    int* __restrict__ cand_i) {
    int tg = gw / KS;
    int chunk = gw % KS;
    int tokA = tg * 128 + lane;
    int tokB = tokA + 64;
    int k0 = chunk * CPK;
    const float4* za = (const float4*)(zflat + (size_t)tokA * 32);
    const float4* zb = (const float4*)(zflat + (size_t)tokB * 32);
    float4 a0 = za[0], a1 = za[1], a2 = za[2], a3 = za[3];
    float4 a4 = za[4], a5 = za[5], a6 = za[6], a7 = za[7];
    float4 b0 = zb[0], b1 = zb[1], b2 = zb[2], b3 = zb[3];
    float4 b4 = zb[4], b5 = zb[5], b6 = zb[6], b7 = zb[7];
    float zsqA = pairwise_zsq(a0, a1, a2, a3, a4, a5, a6, a7);
    float zsqB = pairwise_zsq(b0, b1, b2, b3, b4, b5, b6, b7);
    float bestA = 1e30f, bestB = 1e30f;
    int biA = 0, biB = 0;
#pragma unroll 2
    for (int k = k0; k < k0 + CPK; k++) {
        const float4* wr = (const float4*)emb + (size_t)k * 8;  // uniform
        float4 w0 = wr[0], w1 = wr[1], w2 = wr[2], w3 = wr[3];
        float4 w4 = wr[4], w5 = wr[5], w6 = wr[6], w7 = wr[7];
        float wk = wsq[k];
        float dotA = 0.f, dotB = 0.f;
        DOT32_2(dotA, dotB);
        float dA = __fsub_rn(__fadd_rn(zsqA, wk), __fmul_rn(2.f, dotA));
        float dB = __fsub_rn(__fadd_rn(zsqB, wk), __fmul_rn(2.f, dotB));
        if (dA < bestA) { bestA = dA; biA = k; }  // strict < keeps lowest k
        if (dB < bestB) { bestB = dB; biB = k; }
    }
    cand_d[(size_t)tokA * KS + chunk] = bestA;
    cand_i[(size_t)tokA * KS + chunk] = biA;
    cand_d[(size_t)tokB * KS + chunk] = bestB;
    cand_i[(size_t)tokB * KS + chunk] = biB;
}

// combine: wave gw handles tokens gw, gw+NWAVES, ...; lex-min over [tok][s]
// (associative -> same winner/tie-break as serial ascending scan).
template <int T, int KS>
__device__ __forceinline__ void dev_combine(int gw, int lane,
    const float* __restrict__ cand_d, const int* __restrict__ cand_i,
    const float* __restrict__ emb, float* __restrict__ zq) {
    for (int tok = gw; tok < T; tok += NWAVES) {
        float best = 1e30f;
        int bi = 0x7fffffff;
        for (int s = lane; s < KS; s += 64) {
            float d = cand_d[(size_t)tok * KS + s];
            int i = cand_i[(size_t)tok * KS + s];
            if (d < best || (d == best && i < bi)) { best = d; bi = i; }
        }
        for (int off = 32; off > 0; off >>= 1) {
            float od = __shfl_down(best, off, 64);
            int oi = __shfl_down(bi, off, 64);
            if (od < best || (od == best && oi < bi)) { best = od; bi = oi; }
        }
        bi = __shfl(bi, 0, 64);
        if (lane < 8) {
            ((float4*)zq)[(size_t)tok * 8 + lane] =
                ((const float4*)emb)[(size_t)bi * 8 + lane];
        }
    }
}

// apply: block blk does planes 2blk,2blk+1. Exact original per-plane math.
template <int PN, int PN_NEXT>
__device__ __forceinline__ void dev_apply(int blk, int t,
    const float* __restrict__ zrest_in, const float* __restrict__ zq,
    float* __restrict__ out_lvl, const float* __restrict__ out_prev,
    float* __restrict__ zrest_out, float* __restrict__ zflat_next,
    float* rest) {
    int h = t >> 4, w = t & 15;
    float wy[4], wx[4];
    int iy0 = 0, ny = 0, jx0 = 0, nx = 0;
    if constexpr (PN != 16) {
        taps<PN>(h, wy, iy0, ny);
        taps<PN>(w, wx, jx0, nx);
    }
    for (int it = 0; it < 2; it++) {
        int bc = blk * 2 + it;
        int b = bc >> 5, c = bc & 31;
        float zup;
        if constexpr (PN == 16) {
            zup = zq[(size_t)(((b * 16 + h) * 16 + w)) * 32 + c];
        } else {
            zup = 0.f;
            for (int e = 0; e < nx; e++) {
                float colacc = 0.f;
                for (int a = 0; a < ny; a++)
                    colacc += wy[a] * zq[(size_t)((b * PN + iy0 + a) * PN + (jx0 + e)) * 32 + c];
                zup += wx[e] * colacc;
            }
        }
        int idx = bc * PLANE + t;
        float prev = out_prev ? out_prev[idx] : 0.f;
        out_lvl[idx] = __fadd_rn(prev, zup);

        if (zflat_next) {
            float rv = __fsub_rn(zrest_in[idx], zup);
            rest[t] = rv;
            if (zrest_out) zrest_out[idx] = rv;
            __syncthreads();
            constexpr int S = 16 / PN_NEXT;
            if (t < PN_NEXT * PN_NEXT) {
                int i = t / PN_NEXT, j = t % PN_NEXT;
                float s = 0.f;
                for (int di = 0; di < S; di++)
                    for (int dj = 0; dj < S; dj++)
                        s = __fadd_rn(s, rest[(i * S + di) * 16 + (j * S + dj)]);
                zflat_next[(size_t)((b * PN_NEXT + i) * PN_NEXT + j) * 32 + c] =
                    s * (1.f / (float)(S * S));
            }
            __syncthreads();  // rest[] reused next plane
        }
    }
}

// ==================== fused cooperative kernel ==============================
// 1024 blocks x 256 thr (4096 waves, 4 blocks/CU guaranteed by
// __launch_bounds__(256,4)); grid.sync() replaces each of the 15 kernel
// boundaries (~6-7us each -> ~1-3us each).
__global__ void __launch_bounds__(256, 4) fused_all(
    const float* __restrict__ z_enc, const float* __restrict__ emb,
    float* __restrict__ out, float* __restrict__ wsq,
    float* __restrict__ zflat, float* __restrict__ zq,
    float* __restrict__ zrest, float* __restrict__ cand_d,
    int* __restrict__ cand_i) {
    cg::grid_group grid = cg::this_grid();
    __shared__ float p[4];
    __shared__ float rest[PLANE];
    int t = threadIdx.x;
    int blk = blockIdx.x;
    int lane = t & 63;
    int gw = blk * 4 + (t >> 6);
    const int LVL = NB * NC * PLANE;

    dev_init(blk, t, z_enc, emb, zflat, wsq, p);
    grid.sync();

    // level 0: T=64
    dev_partk<64>(gw, lane, zflat, emb, wsq, cand_d, cand_i);
    grid.sync();
    dev_combine<64, 16>(gw, lane, cand_d, cand_i, emb, zq);
    grid.sync();
    dev_apply<1, 2>(blk, t, z_enc, zq, out, nullptr, zrest, zflat, rest);
    grid.sync();

    // level 1: T=256
    dev_partk<256>(gw, lane, zflat, emb, wsq, cand_d, cand_i);
    grid.sync();
    dev_combine<256, 16>(gw, lane, cand_d, cand_i, emb, zq);
    grid.sync();
    dev_apply<2, 4>(blk, t, zrest, zq, out + LVL, out, zrest, zflat, rest);
    grid.sync();

    // level 2: T=1024, KS=512, CPK=8
    dev_part2<8, 512>(gw, lane, zflat, emb, wsq, cand_d, cand_i);
    grid.sync();
    dev_combine<1024, 512>(gw, lane, cand_d, cand_i, emb, zq);
    grid.sync();
    dev_apply<4, 8>(blk, t, zrest, zq, out + 2 * LVL, out + LVL, zrest, zflat, rest);
    grid.sync();

    // level 3: T=4096, KS=128, CPK=32
    dev_part2<32, 128>(gw, lane, zflat, emb, wsq, cand_d, cand_i);
    grid.sync();
    dev_combine<4096, 128>(gw, lane, cand_d, cand_i, emb, zq);
    grid.sync();
    dev_apply<8, 16>(blk, t, zrest, zq, out + 3 * LVL, out + 2 * LVL, zrest, zflat, rest);
    grid.sync();

    // level 4: T=16384, KS=32, CPK=128
    dev_part2<128, 32>(gw, lane, zflat, emb, wsq, cand_d, cand_i);
    grid.sync();
    dev_combine<16384, 32>(gw, lane, cand_d, cand_i, emb, zq);
    grid.sync();
    dev_apply<16, 16>(blk, t, zrest, zq, out + 4 * LVL, out + 3 * LVL, nullptr, nullptr, rest);
}

// ==================== fallback wrappers (proven 16-launch path) =============
__global__ void __launch_bounds__(256) k_init(
    const float* __restrict__ z_enc, const float* __restrict__ emb,
    float* __restrict__ zflat, float* __restrict__ wsq) {
    __shared__ float p[4];
    dev_init(blockIdx.x, threadIdx.x, z_enc, emb, zflat, wsq, p);
}
template <int T>
__global__ void __launch_bounds__(256, 4) k_partk(
    const float* __restrict__ zflat, const float* __restrict__ emb,
    const float* __restrict__ wsq, float* __restrict__ cand_d,
    int* __restrict__ cand_i) {
    dev_partk<T>(blockIdx.x * 4 + (threadIdx.x >> 6), threadIdx.x & 63,
                 zflat, emb, wsq, cand_d, cand_i);
}
template <int CPK, int KS>
__global__ void __launch_bounds__(256, 4) k_part2(
    const float* __restrict__ zflat, const float* __restrict__ emb,
    const float* __restrict__ wsq, float* __restrict__ cand_d,
    int* __restrict__ cand_i) {
    dev_part2<CPK, KS>(blockIdx.x * 4 + (threadIdx.x >> 6), threadIdx.x & 63,
                       zflat, emb, wsq, cand_d, cand_i);
}
template <int T, int KS>
__global__ void __launch_bounds__(256) k_combine(
    const float* __restrict__ cand_d, const int* __restrict__ cand_i,
    const float* __restrict__ emb, float* __restrict__ zq) {
    dev_combine<T, KS>(blockIdx.x * 4 + (threadIdx.x >> 6), threadIdx.x & 63,
                       cand_d, cand_i, emb, zq);
}
template <int PN, int PN_NEXT>
__global__ void __launch_bounds__(256) k_apply(
    const float* __restrict__ zrest_in, const float* __restrict__ zq,
    float* __restrict__ out_lvl, const float* __restrict__ out_prev,
    float* __restrict__ zrest_out, float* __restrict__ zflat_next) {
    __shared__ float rest[PLANE];
    dev_apply<PN, PN_NEXT>(blockIdx.x, threadIdx.x, zrest_in, zq, out_lvl,
                           out_prev, zrest_out, zflat_next, rest);
}

extern "C" void kernel_launch(void* const* d_in, const int* in_sizes, int n_in,
                              void* d_out, int out_size, void* d_ws, size_t ws_size,
                              hipStream_t stream) {
    const float* z_enc = (const float*)d_in[0];   // [64,32,16,16]
    const float* emb   = (const float*)d_in[1];   // [4096,32]
    float* out = (float*)d_out;                   // [5,64,32,16,16]
    float* ws = (float*)d_ws;

    float* wsq    = ws;                       // 4096
    float* zflat  = wsq + NK;                 // 524288 (token-major, C-last)
    float* zq     = zflat + 524288;           // 524288
    float* zrest  = zq + 524288;              // 524288 (plane layout)
    float* cand_d = zrest + 524288;           // 524288 ([tok][s] layout)
    int*   cand_i = (int*)(cand_d + 524288);  // 524288

    const int LVL = NB * NC * PLANE;

    // ---- preferred: single cooperative kernel, 15 grid.syncs ----
    void* kargs[] = {(void*)&z_enc, (void*)&emb, (void*)&out, (void*)&wsq,
                     (void*)&zflat, (void*)&zq, (void*)&zrest,
                     (void*)&cand_d, (void*)&cand_i};
    hipError_t err = hipLaunchCooperativeKernel(
        (const void*)fused_all, dim3(1024), dim3(256), kargs, 0, stream);
    if (err == hipSuccess) return;

    // ---- fallback: proven 16-launch sequence (same device bodies) ----
    k_init<<<1024, 256, 0, stream>>>(z_enc, emb, zflat, wsq);

    k_partk<64><<<256, 256, 0, stream>>>(zflat, emb, wsq, cand_d, cand_i);
    k_combine<64, 16><<<1024, 256, 0, stream>>>(cand_d, cand_i, emb, zq);
    k_apply<1, 2><<<1024, 256, 0, stream>>>(z_enc, zq, out, nullptr, zrest, zflat);

    k_partk<256><<<1024, 256, 0, stream>>>(zflat, emb, wsq, cand_d, cand_i);
    k_combine<256, 16><<<1024, 256, 0, stream>>>(cand_d, cand_i, emb, zq);
    k_apply<2, 4><<<1024, 256, 0, stream>>>(zrest, zq, out + LVL, out, zrest, zflat);

    k_part2<8, 512><<<1024, 256, 0, stream>>>(zflat, emb, wsq, cand_d, cand_i);
    k_combine<1024, 512><<<1024, 256, 0, stream>>>(cand_d, cand_i, emb, zq);
    k_apply<4, 8><<<1024, 256, 0, stream>>>(zrest, zq, out + 2 * LVL, out + LVL, zrest, zflat);

    k_part2<32, 128><<<1024, 256, 0, stream>>>(zflat, emb, wsq, cand_d, cand_i);
    k_combine<4096, 128><<<1024, 256, 0, stream>>>(cand_d, cand_i, emb, zq);
    k_apply<8, 16><<<1024, 256, 0, stream>>>(zrest, zq, out + 3 * LVL, out + 2 * LVL, zrest, zflat);

    k_part2<128, 32><<<1024, 256, 0, stream>>>(zflat, emb, wsq, cand_d, cand_i);
    k_combine<16384, 32><<<1024, 256, 0, stream>>>(cand_d, cand_i, emb, zq);
    k_apply<16, 16><<<1024, 256, 0, stream>>>(zrest, zq, out + 4 * LVL, out + 3 * LVL, nullptr, nullptr);
}

// Round 11
// 575.400 us; speedup vs baseline: 3.6237x; 3.6237x over previous
//
#include <hip/hip_runtime.h>

#define NB 64      // batch
#define NC 32      // channels
#define PLANE 256  // 16*16
#define NK 4096    // codebook size

// ---------------- cubic (Keys a=-0.5), matches jax.image.resize 'cubic' ----
__device__ __forceinline__ float cubic_w(float x) {
    x = fabsf(x);
    if (x >= 2.f) return 0.f;
    if (x >= 1.f) return ((-0.5f * x + 2.5f) * x - 4.f) * x + 2.f;
    return ((1.5f * x - 2.5f) * x) * x + 1.f;
}

template <int PN>
__device__ __forceinline__ void taps(int o, float* w, int& i0, int& n) {
    float sf = (o + 0.5f) * ((float)PN / 16.f) - 0.5f;
    int lo = (int)floorf(sf) - 1;
    int hi = lo + 3;
    if (lo < 0) lo = 0;
    if (hi > PN - 1) hi = PN - 1;
    n = hi - lo + 1;
    i0 = lo;
    float tot = 0.f;
    for (int i = 0; i < n; i++) {
        float ww = cubic_w(sf - (float)(lo + i));
        w[i] = ww;
        tot += ww;
    }
    float inv = 1.f / tot;
    for (int i = 0; i < n; i++) w[i] *= inv;
}

// ---- exact-order helpers (match numpy reference rounding; do not touch) ----
#define FMA4(D, A, B)                                                          \
    D = __builtin_fmaf((A).x, (B).x, D); D = __builtin_fmaf((A).y, (B).y, D);  \
    D = __builtin_fmaf((A).z, (B).z, D); D = __builtin_fmaf((A).w, (B).w, D)
#define DOT32(D)                                                               \
    FMA4(D, z0, w0); FMA4(D, z1, w1); FMA4(D, z2, w2); FMA4(D, z3, w3);        \
    FMA4(D, z4, w4); FMA4(D, z5, w5); FMA4(D, z6, w6); FMA4(D, z7, w7)
#define DOT32_2(DA, DB)                                                        \
    FMA4(DA, a0, w0); FMA4(DB, b0, w0); FMA4(DA, a1, w1); FMA4(DB, b1, w1);    \
    FMA4(DA, a2, w2); FMA4(DB, b2, w2); FMA4(DA, a3, w3); FMA4(DB, b3, w3);    \
    FMA4(DA, a4, w4); FMA4(DB, b4, w4); FMA4(DA, a5, w5); FMA4(DB, b5, w5);    \
    FMA4(DA, a6, w6); FMA4(DB, b6, w6); FMA4(DA, a7, w7); FMA4(DB, b7, w7)

__device__ __forceinline__ float pairwise_zsq(float4 z0, float4 z1, float4 z2,
                                              float4 z3, float4 z4, float4 z5,
                                              float4 z6, float4 z7) {
#define SQ_(a) __fmul_rn((a), (a))
#define R4_(a, b, c, d) \
    __fadd_rn(__fadd_rn(__fadd_rn(SQ_(a), SQ_(b)), SQ_(c)), SQ_(d))
    float r0 = R4_(z0.x, z2.x, z4.x, z6.x);
    float r1 = R4_(z0.y, z2.y, z4.y, z6.y);
    float r2 = R4_(z0.z, z2.z, z4.z, z6.z);
    float r3 = R4_(z0.w, z2.w, z4.w, z6.w);
    float r4 = R4_(z1.x, z3.x, z5.x, z7.x);
    float r5 = R4_(z1.y, z3.y, z5.y, z7.y);
    float r6 = R4_(z1.z, z3.z, z5.z, z7.z);
    float r7 = R4_(z1.w, z3.w, z5.w, z7.w);
    return __fadd_rn(__fadd_rn(__fadd_rn(r0, r1), __fadd_rn(r2, r3)),
                     __fadd_rn(__fadd_rn(r4, r5), __fadd_rn(r6, r7)));
#undef R4_
#undef SQ_
}

// ---------------- init: plane means of z_enc -> zflat0 ; ||e||^2 -----------
__global__ void __launch_bounds__(256) init_kernel(
    const float* __restrict__ z_enc, const float* __restrict__ emb,
    float* __restrict__ zflat0, float* __restrict__ wsq) {
    int bc = blockIdx.x;
    int t = threadIdx.x;
    float v = z_enc[bc * PLANE + t];
    for (int o = 32; o > 0; o >>= 1) v += __shfl_down(v, o, 64);
    __shared__ float p[4];
    if ((t & 63) == 0) p[t >> 6] = v;
    __syncthreads();
    if (t == 0) zflat0[bc] = (p[0] + p[1] + p[2] + p[3]) * (1.f / 256.f);
    if (t < 64) {
        int k = 2 * bc + (t >> 5);
        int c = t & 31;
        float e = emb[k * 32 + c];
        float s = __fmul_rn(e, e);
        for (int o = 16; o > 0; o >>= 1) s += __shfl_down(s, o, 32);
        if (c == 0) wsq[k] = s;
    }
}

// ---------------- per-batch apply body (exact original per-plane math) ------
// Block handles batch b: loops c = 0..31, each iteration is bit-identical to
// the original one-block-per-(b,c)-plane apply kernel.
template <int PN, int PN_NEXT>
__device__ __forceinline__ void dev_apply_batch(int b, int t,
    const float* __restrict__ zrest_in, const float* __restrict__ zq,
    float* __restrict__ out_lvl, const float* __restrict__ out_prev,
    float* __restrict__ zrest_out, float* __restrict__ zflat_next,
    float* rest) {
    int h = t >> 4, w = t & 15;
    float wy[4], wx[4];
    int iy0 = 0, ny = 0, jx0 = 0, nx = 0;
    if constexpr (PN != 16) {
        taps<PN>(h, wy, iy0, ny);
        taps<PN>(w, wx, jx0, nx);
    }
    for (int c = 0; c < 32; c++) {
        int bc = b * 32 + c;
        float zup;
        if constexpr (PN == 16) {
            zup = zq[(size_t)(((b * 16 + h) * 16 + w)) * 32 + c];
        } else {
            zup = 0.f;
            for (int e = 0; e < nx; e++) {
                float colacc = 0.f;
                for (int a = 0; a < ny; a++)
                    colacc += wy[a] * zq[(size_t)((b * PN + iy0 + a) * PN + (jx0 + e)) * 32 + c];
                zup += wx[e] * colacc;
            }
        }
        int idx = bc * PLANE + t;
        float prev = out_prev ? out_prev[idx] : 0.f;
        out_lvl[idx] = __fadd_rn(prev, zup);

        if (zflat_next) {
            float rv = __fsub_rn(zrest_in[idx], zup);
            rest[t] = rv;
            if (zrest_out) zrest_out[idx] = rv;
            __syncthreads();
            constexpr int S = 16 / PN_NEXT;
            if (t < PN_NEXT * PN_NEXT) {
                int i = t / PN_NEXT, j = t % PN_NEXT;
                float s = 0.f;
                for (int di = 0; di < S; di++)
                    for (int dj = 0; dj < S; dj++)
                        s = __fadd_rn(s, rest[(i * S + di) * 16 + (j * S + dj)]);
                zflat_next[(size_t)((b * PN_NEXT + i) * PN_NEXT + j) * 32 + c] =
                    s * (1.f / (float)(S * S));
            }
            __syncthreads();  // rest[] reused next plane
        }
    }
}

// ---------------- fused level 0: full-scan argmin + apply (64 blocks) -------
// Block b: 4 waves each scan 1024 codes (lane-strided ascending k) for token
// b; block lex-reduce in ascending-chunk order (associative lex-min -> same
// winner/ties as partk+combine); zq row written; then per-batch apply.
// L1 tokens written to SCRATCH (zflat_sc) -- writing them into zflat would
// race with other blocks still reading zflat rows 0..63.
__global__ void __launch_bounds__(256) fused_l0(
    const float* __restrict__ z_enc, const float* __restrict__ emb,
    const float* __restrict__ wsq, const float* __restrict__ zflat,
    float* __restrict__ zq, float* __restrict__ out,
    float* __restrict__ zrest, float* __restrict__ zflat_sc) {
    int b = blockIdx.x, t = threadIdx.x;
    int wave = t >> 6, lane = t & 63;
    __shared__ float sd[4];
    __shared__ int si[4];
    __shared__ int sbi;
    __shared__ float rest[PLANE];

    const float4* zr = (const float4*)(zflat + (size_t)b * 32);  // uniform
    float4 z0 = zr[0], z1 = zr[1], z2 = zr[2], z3 = zr[3];
    float4 z4 = zr[4], z5 = zr[5], z6 = zr[6], z7 = zr[7];
    float zsq = pairwise_zsq(z0, z1, z2, z3, z4, z5, z6, z7);

    float best = 1e30f;
    int bi = 0;
    int kbase = wave * 1024;
#pragma unroll
    for (int j = 0; j < 16; j++) {
        int k = kbase + j * 64 + lane;   // ascending per lane
        const float4* wr = (const float4*)emb + (size_t)k * 8;  // per-lane
        float4 w0 = wr[0], w1 = wr[1], w2 = wr[2], w3 = wr[3];
        float4 w4 = wr[4], w5 = wr[5], w6 = wr[6], w7 = wr[7];
        float dot = 0.f;
        DOT32(dot);
        float d = __fsub_rn(__fadd_rn(zsq, wsq[k]), __fmul_rn(2.f, dot));
        if (d < best) { best = d; bi = k; }
    }
    for (int off = 32; off > 0; off >>= 1) {
        float od = __shfl_down(best, off, 64);
        int oi = __shfl_down(bi, off, 64);
        if (od < best || (od == best && oi < bi)) { best = od; bi = oi; }
    }
    if (lane == 0) { sd[wave] = best; si[wave] = bi; }
    __syncthreads();
    if (t == 0) {
        float bb = 1e30f;
        int ii = 0x7fffffff;
        for (int s = 0; s < 4; s++) {
            float d = sd[s];
            int i2 = si[s];
            if (d < bb || (d == bb && i2 < ii)) { bb = d; ii = i2; }
        }
        sbi = ii;
    }
    __syncthreads();
    if (t < 32) zq[(size_t)b * 32 + t] = emb[(size_t)sbi * 32 + t];
    __syncthreads();

    dev_apply_batch<1, 2>(b, t, z_enc, zq, out, nullptr, zrest, zflat_sc, rest);
}

// ---------------- fused level 1: full-scan argmin + apply (64 blocks) -------
// Block b: wave w full-scans all 4096 codes for token 4b+w (ascending per
// lane), writes zq row; then per-batch apply. Reads L1 tokens from scratch,
// writes L2 tokens into zflat (no reader of zflat in this kernel -> safe).
__global__ void __launch_bounds__(256) fused_l1(
    const float* __restrict__ emb, const float* __restrict__ wsq,
    const float* __restrict__ zflat_sc, float* __restrict__ zq,
    float* __restrict__ out_lvl, const float* __restrict__ out_prev,
    float* __restrict__ zrest, float* __restrict__ zflat) {
    int b = blockIdx.x, t = threadIdx.x;
    int wave = t >> 6, lane = t & 63;
    __shared__ float rest[PLANE];
    int tok = b * 4 + wave;

    const float4* zr = (const float4*)(zflat_sc + (size_t)tok * 32);  // uniform
    float4 z0 = zr[0], z1 = zr[1], z2 = zr[2], z3 = zr[3];
    float4 z4 = zr[4], z5 = zr[5], z6 = zr[6], z7 = zr[7];
    float zsq = pairwise_zsq(z0, z1, z2, z3, z4, z5, z6, z7);

    float best = 1e30f;
    int bi = 0;
#pragma unroll 4
    for (int j = 0; j < 64; j++) {
        int k = j * 64 + lane;   // ascending per lane
        const float4* wr = (const float4*)emb + (size_t)k * 8;  // per-lane
        float4 w0 = wr[0], w1 = wr[1], w2 = wr[2], w3 = wr[3];
        float4 w4 = wr[4], w5 = wr[5], w6 = wr[6], w7 = wr[7];
        float dot = 0.f;
        DOT32(dot);
        float d = __fsub_rn(__fadd_rn(zsq, wsq[k]), __fmul_rn(2.f, dot));
        if (d < best) { best = d; bi = k; }
    }
    for (int off = 32; off > 0; off >>= 1) {
        float od = __shfl_down(best, off, 64);
        int oi = __shfl_down(bi, off, 64);
        if (od < best || (od == best && oi < bi)) { best = od; bi = oi; }
    }
    bi = __shfl(bi, 0, 64);
    if (lane < 8) {
        ((float4*)zq)[(size_t)tok * 8 + lane] =
            ((const float4*)emb)[(size_t)bi * 8 + lane];
    }
    __syncthreads();

    dev_apply_batch<2, 4>(b, t, zrest, zq, out_lvl, out_prev, zrest, zflat, rest);
}

// ---------------- token-parallel argmin partial, 2 tokens/lane (r8) ---------
// 256-thread blocks = 4 waves; k-loop wave-uniform s_loads; exact sequential
// fp32 fma chain per token; strict < over ascending k. Candidates written
// transposed: cand[tok*KS + chunk] (KS = gridDim.y).
template <int CPK>
__global__ void __launch_bounds__(256, 4) part2_kernel(
    const float* __restrict__ zflat, const float* __restrict__ emb,
    const float* __restrict__ wsq, float* __restrict__ cand_d,
    int* __restrict__ cand_i, int T) {
    int wave = threadIdx.x >> 6, lane = threadIdx.x & 63;
    int tokA = (blockIdx.x * 4 + wave) * 128 + lane;
    int tokB = tokA + 64;
    int KS = gridDim.y;
    int k0 = blockIdx.y * CPK;
    const float4* za = (const float4*)(zflat + (size_t)tokA * 32);
    const float4* zb = (const float4*)(zflat + (size_t)tokB * 32);
    float4 a0 = za[0], a1 = za[1], a2 = za[2], a3 = za[3];
    float4 a4 = za[4], a5 = za[5], a6 = za[6], a7 = za[7];
    float4 b0 = zb[0], b1 = zb[1], b2 = zb[2], b3 = zb[3];
    float4 b4 = zb[4], b5 = zb[5], b6 = zb[6], b7 = zb[7];
    float zsqA = pairwise_zsq(a0, a1, a2, a3, a4, a5, a6, a7);
    float zsqB = pairwise_zsq(b0, b1, b2, b3, b4, b5, b6, b7);

    float bestA = 1e30f, bestB = 1e30f;
    int biA = 0, biB = 0;
#pragma unroll 2
    for (int k = k0; k < k0 + CPK; k++) {
        const float4* wr = (const float4*)emb + (size_t)k * 8;  // uniform
        float4 w0 = wr[0], w1 = wr[1], w2 = wr[2], w3 = wr[3];
        float4 w4 = wr[4], w5 = wr[5], w6 = wr[6], w7 = wr[7];
        float wk = wsq[k];
        float dotA = 0.f, dotB = 0.f;
        DOT32_2(dotA, dotB);
        float dA = __fsub_rn(__fadd_rn(zsqA, wk), __fmul_rn(2.f, dotA));
        float dB = __fsub_rn(__fadd_rn(zsqB, wk), __fmul_rn(2.f, dotB));
        if (dA < bestA) { bestA = dA; biA = k; }  // strict < keeps lowest k
        if (dB < bestB) { bestB = dB; biB = k; }
    }
    cand_d[(size_t)tokA * KS + blockIdx.y] = bestA;
    cand_i[(size_t)tokA * KS + blockIdx.y] = biA;
    cand_d[(size_t)tokB * KS + blockIdx.y] = bestB;
    cand_i[(size_t)tokB * KS + blockIdx.y] = biB;
}

// ---------------- fused combine + apply per level (64 blocks) ---------------
// Block b: waves lex-combine the [tok][s] candidates for batch b's PN*PN
// tokens (identical math/ties to combine_wave), write zq rows; syncthreads
// (same-CU visibility); then per-batch apply.
template <int PN, int PN_NEXT, int KS>
__global__ void __launch_bounds__(256) ca_kernel(
    const float* __restrict__ cand_d, const int* __restrict__ cand_i,
    const float* __restrict__ emb, float* __restrict__ zq,
    const float* __restrict__ zrest_in, float* __restrict__ out_lvl,
    const float* __restrict__ out_prev, float* __restrict__ zrest_out,
    float* __restrict__ zflat_next) {
    int b = blockIdx.x, t = threadIdx.x;
    int wave = t >> 6, lane = t & 63;
    __shared__ float rest[PLANE];
    constexpr int PT = PN * PN;

    for (int tl = wave; tl < PT; tl += 4) {
        int tok = b * PT + tl;
        float best = 1e30f;
        int bi = 0x7fffffff;
        for (int s = lane; s < KS; s += 64) {
            float d = cand_d[(size_t)tok * KS + s];
            int i = cand_i[(size_t)tok * KS + s];
            if (d < best || (d == best && i < bi)) { best = d; bi = i; }
        }
        for (int off = 32; off > 0; off >>= 1) {
            float od = __shfl_down(best, off, 64);
            int oi = __shfl_down(bi, off, 64);
            if (od < best || (od == best && oi < bi)) { best = od; bi = oi; }
        }
        bi = __shfl(bi, 0, 64);
        if (lane < 8) {
            ((float4*)zq)[(size_t)tok * 8 + lane] =
                ((const float4*)emb)[(size_t)bi * 8 + lane];
        }
    }
    __syncthreads();

    dev_apply_batch<PN, PN_NEXT>(b, t, zrest_in, zq, out_lvl, out_prev,
                                 zrest_out, zflat_next, rest);
}

extern "C" void kernel_launch(void* const* d_in, const int* in_sizes, int n_in,
                              void* d_out, int out_size, void* d_ws, size_t ws_size,
                              hipStream_t stream) {
    const float* z_enc = (const float*)d_in[0];   // [64,32,16,16]
    const float* emb   = (const float*)d_in[1];   // [4096,32]
    float* out = (float*)d_out;                   // [5,64,32,16,16]
    float* ws = (float*)d_ws;

    float* wsq    = ws;                       // 4096
    float* zflat  = wsq + NK;                 // 524288 (token-major, C-last)
    float* zq     = zflat + 524288;           // 524288
    float* zrest  = zq + 524288;              // 524288 (plane layout)
    float* cand_d = zrest + 524288;           // 524288 ([tok][s]; L1-tok scratch pre-L2)
    int*   cand_i = (int*)(cand_d + 524288);  // 524288

    const int LVL = NB * NC * PLANE;  // 524288 elems per output level

    init_kernel<<<2048, 256, 0, stream>>>(z_enc, emb, zflat, wsq);

    // level 0: fused full-scan + apply; L1 tokens -> scratch (cand_d region)
    fused_l0<<<64, 256, 0, stream>>>(z_enc, emb, wsq, zflat, zq, out, zrest, cand_d);

    // level 1: fused full-scan (reads scratch) + apply; L2 tokens -> zflat
    fused_l1<<<64, 256, 0, stream>>>(emb, wsq, cand_d, zq, out + LVL, out, zrest, zflat);

    // level 2: T=1024, KS=512, CPK=8
    part2_kernel<8><<<dim3(2, 512), 256, 0, stream>>>(zflat, emb, wsq, cand_d, cand_i, 1024);
    ca_kernel<4, 8, 512><<<64, 256, 0, stream>>>(cand_d, cand_i, emb, zq,
        zrest, out + 2 * LVL, out + LVL, zrest, zflat);

    // level 3: T=4096, KS=128, CPK=32
    part2_kernel<32><<<dim3(8, 128), 256, 0, stream>>>(zflat, emb, wsq, cand_d, cand_i, 4096);
    ca_kernel<8, 16, 128><<<64, 256, 0, stream>>>(cand_d, cand_i, emb, zq,
        zrest, out + 3 * LVL, out + 2 * LVL, zrest, zflat);

    // level 4: T=16384, KS=32, CPK=128
    part2_kernel<128><<<dim3(32, 32), 256, 0, stream>>>(zflat, emb, wsq, cand_d, cand_i, 16384);
    ca_kernel<16, 16, 32><<<64, 256, 0, stream>>>(cand_d, cand_i, emb, zq,
        zrest, out + 4 * LVL, out + 3 * LVL, nullptr, nullptr);
}